// Round 1
// baseline (147.941 us; speedup 1.0000x reference)
//
#include <hip/hip_runtime.h>
#include <math.h>

#define NC 80
#define NA 3
#define BATCH 16
#define NGT 32
#define IOU_THR 0.5f
#define FEPS 1e-7f
#define CAP 1536   // per-scale positive capacity = B*NA*NGT

// ws layout (as int/float words):
//   F[0..2]  box_sum per scale
//   F[3..5]  cls_sum per scale
//   F[6..8]  obj_num per scale
//   I[16..18] n_valid per scale
//   I[19..21] n_pos per scale (also list append counter)
//   I[32 .. 32+3*CAP) positive-cell list, packed int per entry
#define OFF_NV 16
#define OFF_NP 19
#define OFF_LIST 32

__device__ __forceinline__ float bce_f(float x, float t) {
    return fmaxf(x, 0.f) - x * t + log1pf(expf(-fabsf(x)));
}

__global__ __launch_bounds__(128) void assign_kernel(
    const float* __restrict__ gt_boxes,
    const float* __restrict__ a0, const float* __restrict__ a1, const float* __restrict__ a2,
    int* __restrict__ ws_i)
{
    const int blk = blockIdx.x;       // B*3 blocks
    const int si = blk % 3;
    const int b  = blk / 3;
    const int W  = 80 >> si;          // 80,40,20
    const int HW = W * W;
    const float s = (float)(8 << si);
    const float* anch = (si == 0) ? a0 : (si == 1) ? a1 : a2;

    __shared__ float gtb[NGT][4];
    __shared__ int   gflat[NGT];
    __shared__ float giou[NA][NGT];
    __shared__ float gcand[NA][NGT];
    __shared__ unsigned char gpos[NA][NGT];
    __shared__ unsigned char gisb[NA][NGT];

    const int t = threadIdx.x;
    // load 32 GT boxes (128 floats) cooperatively
    gtb[t >> 2][t & 3] = gt_boxes[b * NGT * 4 + t];
    __syncthreads();

    if (t < NGT) {
        float x1 = gtb[t][0], y1 = gtb[t][1], x2 = gtb[t][2], y2 = gtb[t][3];
        float gcx = (x1 + x2) * 0.5f, gcy = (y1 + y2) * 0.5f;
        int gx = (int)(gcx / s); gx = min(max(gx, 0), W - 1);
        int gy = (int)(gcy / s); gy = min(max(gy, 0), W - 1);
        gflat[t] = gy * W + gx;
    }
    __syncthreads();

    if (t < NA * NGT) {
        int a = t >> 5, n = t & 31;
        int flat = gflat[n];
        const float* ap = anch + ((size_t)a * HW + flat) * 4;
        float acx = ap[0], acy = ap[1], aw = ap[2], ah = ap[3];
        float ax1 = acx - aw * 0.5f, ay1 = acy - ah * 0.5f;
        float ax2 = acx + aw * 0.5f, ay2 = acy + ah * 0.5f;
        float x1 = gtb[n][0], y1 = gtb[n][1], x2 = gtb[n][2], y2 = gtb[n][3];
        float iw = fmaxf(fminf(x2, ax2) - fmaxf(x1, ax1), 0.f);
        float ih = fmaxf(fminf(y2, ay2) - fmaxf(y1, ay1), 0.f);
        float inter = iw * ih;
        float a_gt = (x2 - x1) * (y2 - y1);
        float a_an = aw * ah;
        giou[a][n] = inter / (a_gt + a_an - inter + FEPS);
    }
    __syncthreads();

    if (t < NA * NGT) {
        int a = t >> 5, n = t & 31;
        float i0 = giou[0][n], i1 = giou[1][n], i2 = giou[2][n];
        bool has = (i0 > IOU_THR) || (i1 > IOU_THR) || (i2 > IOU_THR);
        int amax = 0; float bv = i0;                    // first-max like jnp.argmax
        if (i1 > bv) { bv = i1; amax = 1; }
        if (i2 > bv) { bv = i2; amax = 2; }
        float iou = giou[a][n];
        bool p = has ? (iou > IOU_THR) : (a == amax);
        gpos[a][n] = p ? 1 : 0;
        gcand[a][n] = p ? iou : -1.0f;
    }
    __syncthreads();

    if (t < NA * NGT) {
        int a = t >> 5, n = t & 31;
        int flat = gflat[n];
        float best = -1.0f;                             // scatter-max init
        for (int m = 0; m < NGT; ++m)
            if (gflat[m] == flat) best = fmaxf(best, gcand[a][m]);
        gisb[a][n] = (gpos[a][n] && gcand[a][n] >= best) ? 1 : 0;
    }
    __syncthreads();

    if (t < NA * NGT) {
        int a = t >> 5, n = t & 31;
        if (gisb[a][n]) {
            int flat = gflat[n];
            bool first = true;                          // win = min gt index among isb
            for (int m = 0; m < n; ++m)
                if (gflat[m] == flat && gisb[a][m]) { first = false; break; }
            if (first) {
                int k = atomicAdd(&ws_i[OFF_NP + si], 1);
                ws_i[OFF_LIST + si * CAP + k] = flat | (a << 13) | (b << 15) | (n << 19);
            }
        }
    }
}

__global__ __launch_bounds__(256) void objbase_kernel(
    const float* __restrict__ p0, const float* __restrict__ p1,
    const float* __restrict__ p2, float* __restrict__ ws_f)
{
    // block ranges: [0,1200) scale0, [1200,1500) scale1, [1500,1575) scale2
    int bid = blockIdx.x;
    int si, base; const float* p;
    if (bid < 1200)      { si = 0; base = bid;        p = p0; }
    else if (bid < 1500) { si = 1; base = bid - 1200; p = p1; }
    else                 { si = 2; base = bid - 1500; p = p2; }
    int local = base * 256 + threadIdx.x;
    float x = p[(size_t)local * (5 + NC) + 4];
    float val = 0.5f * bce_f(x, 0.f);   // NOOBJ_W * BCE(x, 0)
    for (int off = 32; off; off >>= 1) val += __shfl_down(val, off);
    __shared__ float red[4];
    int lane = threadIdx.x & 63, wv = threadIdx.x >> 6;
    if (lane == 0) red[wv] = val;
    __syncthreads();
    if (threadIdx.x == 0)
        atomicAdd(&ws_f[6 + si], red[0] + red[1] + red[2] + red[3]);
}

__global__ __launch_bounds__(256) void posloss_kernel(
    const float* __restrict__ p0, const float* __restrict__ p1, const float* __restrict__ p2,
    const float* __restrict__ a0, const float* __restrict__ a1, const float* __restrict__ a2,
    const float* __restrict__ gt_boxes, const int* __restrict__ gt_labels,
    float* __restrict__ ws_f, int* __restrict__ ws_i)
{
    int tid = blockIdx.x * blockDim.x + threadIdx.x;
    int si = tid / CAP, k = tid % CAP;
    if (si >= 3) return;
    if (k >= ws_i[OFF_NP + si]) return;
    int e = ws_i[OFF_LIST + si * CAP + k];
    int flat = e & 0x1FFF;
    int a = (e >> 13) & 3;
    int b = (e >> 15) & 15;
    int n = (e >> 19) & 31;
    const int W = 80 >> si;
    const int HW = W * W;
    const float s = (float)(8 << si);
    const float* pred = ((si == 0) ? p0 : (si == 1) ? p1 : p2)
                        + (size_t)((b * NA + a) * HW + flat) * (5 + NC);
    const float* ap = ((si == 0) ? a0 : (si == 1) ? a1 : a2)
                      + ((size_t)a * HW + flat) * 4;

    // decode
    float acx = ap[0], acy = ap[1], aw = ap[2], ah = ap[3];
    float s0 = 1.f / (1.f + expf(-pred[0]));
    float s1 = 1.f / (1.f + expf(-pred[1]));
    float s2 = 1.f / (1.f + expf(-pred[2]));
    float s3 = 1.f / (1.f + expf(-pred[3]));
    float cx = acx + (s0 * 2.f - 0.5f) * s;
    float cy = acy + (s1 * 2.f - 0.5f) * s;
    float pw = aw * (s2 * 2.f) * (s2 * 2.f);
    float ph = ah * (s3 * 2.f) * (s3 * 2.f);
    float b1x1 = cx - pw * 0.5f, b1y1 = cy - ph * 0.5f;
    float b1x2 = cx + pw * 0.5f, b1y2 = cy + ph * 0.5f;
    const float* gb = gt_boxes + (size_t)(b * NGT + n) * 4;
    float b2x1 = gb[0], b2y1 = gb[1], b2x2 = gb[2], b2y2 = gb[3];

    // ciou(b1=pred, b2=gt)
    float w1 = b1x2 - b1x1, h1 = b1y2 - b1y1;
    float w2 = b2x2 - b2x1, h2 = b2y2 - b2y1;
    float iw = fmaxf(fminf(b1x2, b2x2) - fmaxf(b1x1, b2x1), 0.f);
    float ih = fmaxf(fminf(b1y2, b2y2) - fmaxf(b1y1, b2y1), 0.f);
    float inter = iw * ih;
    float uni = w1 * h1 + w2 * h2 - inter + FEPS;
    float iou = inter / uni;
    float cw = fmaxf(b1x2, b2x2) - fminf(b1x1, b2x1);
    float ch = fmaxf(b1y2, b2y2) - fminf(b1y1, b2y1);
    float c2 = cw * cw + ch * ch + FEPS;
    float dx = b2x1 + b2x2 - b1x1 - b1x2;
    float dy = b2y1 + b2y2 - b1y1 - b1y2;
    float rho2 = (dx * dx + dy * dy) * 0.25f;
    const float PI = 3.14159265358979323846f;
    float dv = atanf(w2 / (h2 + FEPS)) - atanf(w1 / (h1 + FEPS));
    float v = (4.f / (PI * PI)) * dv * dv;
    float alpha = v / (v - iou + (1.f + FEPS));
    float ciou = iou - rho2 / c2 - alpha * v;

    if (isfinite(ciou)) {
        atomicAdd(&ws_f[si], 1.f - ciou);
        atomicAdd(&ws_i[OFF_NV + si], 1);
    }

    // cls BCE over 80 channels (one-hot target, LS=0)
    int label = gt_labels[b * NGT + n];
    float csum = 0.f;
    for (int c = 0; c < NC; ++c) {
        float x = pred[5 + c];
        csum += bce_f(x, (c == label) ? 1.f : 0.f);
    }
    atomicAdd(&ws_f[3 + si], csum);

    // obj correction: full-weight BCE(x,1) replaces the 0.5*BCE(x,0) base term
    float ox = pred[4];
    atomicAdd(&ws_f[6 + si], bce_f(ox, 1.f) - 0.5f * bce_f(ox, 0.f));
}

__global__ void final_kernel(const float* __restrict__ ws_f,
                             const int* __restrict__ ws_i, float* __restrict__ out)
{
    if (threadIdx.x != 0 || blockIdx.x != 0) return;
    float bl = 0.f, ol = 0.f, cl = 0.f;
    int tv = 0;
    for (int si = 0; si < 3; ++si) {
        int W = 80 >> si;
        int total = BATCH * NA * W * W;
        int nv   = ws_i[OFF_NV + si];
        int npos = ws_i[OFF_NP + si];
        float box_loss = ws_f[si] / (float)max(nv, 1);
        float wsum = (float)npos + 0.5f * (float)(total - npos);
        float obj_loss = ws_f[6 + si] / (wsum + 1e-6f);
        float cls_loss = ws_f[3 + si] / (float)max(npos * NC, 1);
        bl += box_loss; ol += obj_loss; cl += cls_loss; tv += nv;
    }
    if (tv > 0) { bl /= 3.f; cl /= 3.f; }
    ol /= 3.f;
    float total = 0.15f * bl + 5.0f * ol + 0.5f * cl;
    out[0] = isfinite(total) ? total : 0.f;
}

extern "C" void kernel_launch(void* const* d_in, const int* in_sizes, int n_in,
                              void* d_out, int out_size, void* d_ws, size_t ws_size,
                              hipStream_t stream) {
    const float* p0  = (const float*)d_in[0];
    const float* p1  = (const float*)d_in[1];
    const float* p2  = (const float*)d_in[2];
    const float* a0  = (const float*)d_in[3];
    const float* a1  = (const float*)d_in[4];
    const float* a2  = (const float*)d_in[5];
    const float* gtb = (const float*)d_in[6];
    const int*   gtl = (const int*)d_in[7];
    float* out  = (float*)d_out;
    float* ws_f = (float*)d_ws;
    int*   ws_i = (int*)d_ws;

    hipMemsetAsync(d_ws, 0, 128, stream);  // accumulators + counters
    assign_kernel<<<BATCH * 3, 128, 0, stream>>>(gtb, a0, a1, a2, ws_i);
    objbase_kernel<<<1575, 256, 0, stream>>>(p0, p1, p2, ws_f);
    posloss_kernel<<<(3 * CAP + 255) / 256, 256, 0, stream>>>(
        p0, p1, p2, a0, a1, a2, gtb, gtl, ws_f, ws_i);
    final_kernel<<<1, 64, 0, stream>>>(ws_f, ws_i, out);
}

// Round 2
// 30.818 us; speedup vs baseline: 4.8004x; 4.8004x over previous
//
#include <hip/hip_runtime.h>
#include <math.h>

#define NC 80
#define NA 3
#define BATCH 16
#define NGT 32
#define IOU_THR 0.5f
#define FEPS 1e-7f
#define CAP 1536   // per-scale positive capacity = B*NA*NGT

// ws layout (32-bit words):
//   I[0..2]            n_pos per scale (list append counters)
//   F[ACC_BOX + 16*si] box_sum per scale   (64B apart to avoid same-line atomic pileup)
//   F[ACC_CLS + 16*si] cls_sum per scale
//   F[ACC_OBJ + 16*si] obj_sum per scale
//   F[ACC_NV  + 16*si] n_valid per scale (float count)
//   I[OFF_LIST ..]     positive-cell list (3*CAP ints)
#define OFF_NP   0
#define ACC_BOX  16
#define ACC_CLS  64
#define ACC_OBJ  112
#define ACC_NV   160
#define OFF_LIST 256

#define OBJ_BLOCKS 168   // 128 (s0) + 32 (s1) + 8 (s2), 2400 elements each
#define POS_BLOCKS 288   // 96 per scale; 16 cells/block, 16 lanes/cell

__device__ __forceinline__ float bce_f(float x, float t) {
    return fmaxf(x, 0.f) - x * t + log1pf(expf(-fabsf(x)));
}

__global__ __launch_bounds__(128) void assign_kernel(
    const float* __restrict__ gt_boxes,
    const float* __restrict__ a0, const float* __restrict__ a1, const float* __restrict__ a2,
    int* __restrict__ ws_i)
{
    const int blk = blockIdx.x;       // B*3 blocks
    const int si = blk % 3;
    const int b  = blk / 3;
    const int W  = 80 >> si;          // 80,40,20
    const int HW = W * W;
    const float s = (float)(8 << si);
    const float* anch = (si == 0) ? a0 : (si == 1) ? a1 : a2;

    __shared__ float gtb[NGT][4];
    __shared__ int   gflat[NGT];
    __shared__ float giou[NA][NGT];
    __shared__ float gcand[NA][NGT];
    __shared__ unsigned char gpos[NA][NGT];
    __shared__ unsigned char gisb[NA][NGT];
    __shared__ int wcnt[2];
    __shared__ int wbase;

    const int t = threadIdx.x;
    gtb[t >> 2][t & 3] = gt_boxes[b * NGT * 4 + t];
    __syncthreads();

    if (t < NGT) {
        float x1 = gtb[t][0], y1 = gtb[t][1], x2 = gtb[t][2], y2 = gtb[t][3];
        float gcx = (x1 + x2) * 0.5f, gcy = (y1 + y2) * 0.5f;
        int gx = (int)(gcx / s); gx = min(max(gx, 0), W - 1);
        int gy = (int)(gcy / s); gy = min(max(gy, 0), W - 1);
        gflat[t] = gy * W + gx;
    }
    __syncthreads();

    if (t < NA * NGT) {
        int a = t >> 5, n = t & 31;
        int flat = gflat[n];
        const float* ap = anch + ((size_t)a * HW + flat) * 4;
        float acx = ap[0], acy = ap[1], aw = ap[2], ah = ap[3];
        float ax1 = acx - aw * 0.5f, ay1 = acy - ah * 0.5f;
        float ax2 = acx + aw * 0.5f, ay2 = acy + ah * 0.5f;
        float x1 = gtb[n][0], y1 = gtb[n][1], x2 = gtb[n][2], y2 = gtb[n][3];
        float iw = fmaxf(fminf(x2, ax2) - fmaxf(x1, ax1), 0.f);
        float ih = fmaxf(fminf(y2, ay2) - fmaxf(y1, ay1), 0.f);
        float inter = iw * ih;
        float a_gt = (x2 - x1) * (y2 - y1);
        float a_an = aw * ah;
        giou[a][n] = inter / (a_gt + a_an - inter + FEPS);
    }
    __syncthreads();

    if (t < NA * NGT) {
        int a = t >> 5, n = t & 31;
        float i0 = giou[0][n], i1 = giou[1][n], i2 = giou[2][n];
        bool has = (i0 > IOU_THR) || (i1 > IOU_THR) || (i2 > IOU_THR);
        int amax = 0; float bv = i0;                    // first-max like jnp.argmax
        if (i1 > bv) { bv = i1; amax = 1; }
        if (i2 > bv) { bv = i2; amax = 2; }
        float iou = giou[a][n];
        bool p = has ? (iou > IOU_THR) : (a == amax);
        gpos[a][n] = p ? 1 : 0;
        gcand[a][n] = p ? iou : -1.0f;
    }
    __syncthreads();

    if (t < NA * NGT) {
        int a = t >> 5, n = t & 31;
        int flat = gflat[n];
        float best = -1.0f;                             // scatter-max init
        for (int m = 0; m < NGT; ++m)
            if (gflat[m] == flat) best = fmaxf(best, gcand[a][m]);
        gisb[a][n] = (gpos[a][n] && gcand[a][n] >= best) ? 1 : 0;
    }
    __syncthreads();

    // winner detection + ballot-compacted append (1 atomic per block)
    int win = 0;
    if (t < NA * NGT) {
        int a = t >> 5, n = t & 31;
        if (gisb[a][n]) {
            int flat = gflat[n];
            bool first = true;                          // win = min gt index among isb
            for (int m = 0; m < n; ++m)
                if (gflat[m] == flat && gisb[a][m]) { first = false; break; }
            win = first ? 1 : 0;
        }
    }
    unsigned long long mask = __ballot(win);
    int wv = t >> 6, lane = t & 63;
    if (lane == 0) wcnt[wv] = (int)__popcll(mask);
    __syncthreads();
    if (t == 0) wbase = atomicAdd(&ws_i[OFF_NP + si], wcnt[0] + wcnt[1]);
    __syncthreads();
    if (win) {
        int a = t >> 5, n = t & 31;
        int prefix = (int)__popcll(mask & ((1ull << lane) - 1ull));
        int idx = wbase + (wv ? wcnt[0] : 0) + prefix;
        ws_i[OFF_LIST + si * CAP + idx] = gflat[n] | (a << 13) | (b << 15) | (n << 19);
    }
}

__global__ __launch_bounds__(256) void loss_kernel(
    const float* __restrict__ p0, const float* __restrict__ p1, const float* __restrict__ p2,
    const float* __restrict__ a0, const float* __restrict__ a1, const float* __restrict__ a2,
    const float* __restrict__ gt_boxes, const int* __restrict__ gt_labels,
    float* __restrict__ ws_f, const int* __restrict__ ws_i)
{
    const int bid = blockIdx.x;
    const int t = threadIdx.x;
    __shared__ float red[4][4];

    if (bid < OBJ_BLOCKS) {
        // ---- noobj base sweep: 0.5 * BCE(obj_logit, 0) over all cells ----
        int si, blk_local; const float* p;
        if (bid < 128)      { si = 0; blk_local = bid;       p = p0; }
        else if (bid < 160) { si = 1; blk_local = bid - 128; p = p1; }
        else                { si = 2; blk_local = bid - 160; p = p2; }
        int base_e = blk_local * 2400;
        float acc = 0.f;
        #pragma unroll 2
        for (int i = t; i < 2400; i += 256) {
            float x = p[(size_t)(base_e + i) * (5 + NC) + 4];
            acc += 0.5f * bce_f(x, 0.f);
        }
        for (int off = 32; off; off >>= 1) acc += __shfl_down(acc, off);
        int lane = t & 63, wv = t >> 6;
        if (lane == 0) red[0][wv] = acc;
        __syncthreads();
        if (t == 0)
            atomicAdd(&ws_f[ACC_OBJ + si * 16], red[0][0] + red[0][1] + red[0][2] + red[0][3]);
        return;
    }

    // ---- positive-cell losses: 16 lanes per cell ----
    int pbid = bid - OBJ_BLOCKS;          // [0, 288)
    int si = pbid / 96;
    int blk_in_scale = pbid % 96;
    int np = ws_i[OFF_NP + si];
    if (blk_in_scale * 16 >= np) return;  // whole block inactive

    int g = t >> 4;                       // group (cell slot) within block
    int l16 = t & 15;
    int k = blk_in_scale * 16 + g;
    bool active = (k < np);

    float v_box = 0.f, v_nv = 0.f, v_cls = 0.f, v_obj = 0.f;
    if (active) {
        int e = ws_i[OFF_LIST + si * CAP + k];
        int flat = e & 0x1FFF;
        int a = (e >> 13) & 3;
        int b = (e >> 15) & 15;
        int n = (e >> 19) & 31;
        const int W = 80 >> si;
        const int HW = W * W;
        const float s = (float)(8 << si);
        const float* pred = ((si == 0) ? p0 : (si == 1) ? p1 : p2)
                            + (size_t)((b * NA + a) * HW + flat) * (5 + NC);

        // cls BCE: 5 coalesced channels per lane
        int label = gt_labels[b * NGT + n];
        float csum = 0.f;
        #pragma unroll
        for (int j = 0; j < 5; ++j) {
            int c = l16 + 16 * j;
            float x = pred[5 + c];
            csum += bce_f(x, (c == label) ? 1.f : 0.f);
        }
        #pragma unroll
        for (int m = 8; m; m >>= 1) csum += __shfl_xor(csum, m);

        // decode + ciou + obj correction (redundant on 16 lanes; lane 0 contributes)
        const float* ap = ((si == 0) ? a0 : (si == 1) ? a1 : a2)
                          + ((size_t)a * HW + flat) * 4;
        float acx = ap[0], acy = ap[1], aw = ap[2], ah = ap[3];
        float s0 = 1.f / (1.f + expf(-pred[0]));
        float s1 = 1.f / (1.f + expf(-pred[1]));
        float s2 = 1.f / (1.f + expf(-pred[2]));
        float s3 = 1.f / (1.f + expf(-pred[3]));
        float cx = acx + (s0 * 2.f - 0.5f) * s;
        float cy = acy + (s1 * 2.f - 0.5f) * s;
        float pw = aw * (s2 * 2.f) * (s2 * 2.f);
        float ph = ah * (s3 * 2.f) * (s3 * 2.f);
        float b1x1 = cx - pw * 0.5f, b1y1 = cy - ph * 0.5f;
        float b1x2 = cx + pw * 0.5f, b1y2 = cy + ph * 0.5f;
        const float* gb = gt_boxes + (size_t)(b * NGT + n) * 4;
        float b2x1 = gb[0], b2y1 = gb[1], b2x2 = gb[2], b2y2 = gb[3];

        float w1 = b1x2 - b1x1, h1 = b1y2 - b1y1;
        float w2 = b2x2 - b2x1, h2 = b2y2 - b2y1;
        float iw = fmaxf(fminf(b1x2, b2x2) - fmaxf(b1x1, b2x1), 0.f);
        float ih = fmaxf(fminf(b1y2, b2y2) - fmaxf(b1y1, b2y1), 0.f);
        float inter = iw * ih;
        float uni = w1 * h1 + w2 * h2 - inter + FEPS;
        float iou = inter / uni;
        float cw = fmaxf(b1x2, b2x2) - fminf(b1x1, b2x1);
        float ch = fmaxf(b1y2, b2y2) - fminf(b1y1, b2y1);
        float c2 = cw * cw + ch * ch + FEPS;
        float dx = b2x1 + b2x2 - b1x1 - b1x2;
        float dy = b2y1 + b2y2 - b1y1 - b1y2;
        float rho2 = (dx * dx + dy * dy) * 0.25f;
        const float PI = 3.14159265358979323846f;
        float dv = atanf(w2 / (h2 + FEPS)) - atanf(w1 / (h1 + FEPS));
        float v = (4.f / (PI * PI)) * dv * dv;
        float alpha = v / (v - iou + (1.f + FEPS));
        float ciou = iou - rho2 / c2 - alpha * v;

        if (l16 == 0) {
            if (isfinite(ciou)) { v_box = 1.f - ciou; v_nv = 1.f; }
            v_cls = csum;
            float ox = pred[4];
            v_obj = bce_f(ox, 1.f) - 0.5f * bce_f(ox, 0.f);
        }
    }

    // block-level reduce of 4 values, then 4 atomics (64B-separated addresses)
    int lane = t & 63, wv = t >> 6;
    #pragma unroll
    for (int off = 32; off; off >>= 1) {
        v_box += __shfl_down(v_box, off);
        v_nv  += __shfl_down(v_nv,  off);
        v_cls += __shfl_down(v_cls, off);
        v_obj += __shfl_down(v_obj, off);
    }
    if (lane == 0) { red[0][wv] = v_box; red[1][wv] = v_nv; red[2][wv] = v_cls; red[3][wv] = v_obj; }
    __syncthreads();
    if (t == 0) {
        atomicAdd(&ws_f[ACC_BOX + si * 16], red[0][0] + red[0][1] + red[0][2] + red[0][3]);
        atomicAdd(&ws_f[ACC_NV  + si * 16], red[1][0] + red[1][1] + red[1][2] + red[1][3]);
        atomicAdd(&ws_f[ACC_CLS + si * 16], red[2][0] + red[2][1] + red[2][2] + red[2][3]);
        atomicAdd(&ws_f[ACC_OBJ + si * 16], red[3][0] + red[3][1] + red[3][2] + red[3][3]);
    }
}

__global__ void final_kernel(const float* __restrict__ ws_f,
                             const int* __restrict__ ws_i, float* __restrict__ out)
{
    if (threadIdx.x != 0 || blockIdx.x != 0) return;
    float bl = 0.f, ol = 0.f, cl = 0.f;
    int tv = 0;
    for (int si = 0; si < 3; ++si) {
        int W = 80 >> si;
        int total = BATCH * NA * W * W;
        float nv = ws_f[ACC_NV + si * 16];
        int npos = ws_i[OFF_NP + si];
        float box_loss = ws_f[ACC_BOX + si * 16] / fmaxf(nv, 1.f);
        float wsum = (float)npos + 0.5f * (float)(total - npos);
        float obj_loss = ws_f[ACC_OBJ + si * 16] / (wsum + 1e-6f);
        float cls_loss = ws_f[ACC_CLS + si * 16] / (float)max(npos * NC, 1);
        bl += box_loss; ol += obj_loss; cl += cls_loss; tv += (int)nv;
    }
    if (tv > 0) { bl /= 3.f; cl /= 3.f; }
    ol /= 3.f;
    float total = 0.15f * bl + 5.0f * ol + 0.5f * cl;
    out[0] = isfinite(total) ? total : 0.f;
}

extern "C" void kernel_launch(void* const* d_in, const int* in_sizes, int n_in,
                              void* d_out, int out_size, void* d_ws, size_t ws_size,
                              hipStream_t stream) {
    const float* p0  = (const float*)d_in[0];
    const float* p1  = (const float*)d_in[1];
    const float* p2  = (const float*)d_in[2];
    const float* a0  = (const float*)d_in[3];
    const float* a1  = (const float*)d_in[4];
    const float* a2  = (const float*)d_in[5];
    const float* gtb = (const float*)d_in[6];
    const int*   gtl = (const int*)d_in[7];
    float* out  = (float*)d_out;
    float* ws_f = (float*)d_ws;
    int*   ws_i = (int*)d_ws;

    hipMemsetAsync(d_ws, 0, 1024, stream);  // counters + accumulators (words 0..255)
    assign_kernel<<<BATCH * 3, 128, 0, stream>>>(gtb, a0, a1, a2, ws_i);
    loss_kernel<<<OBJ_BLOCKS + POS_BLOCKS, 256, 0, stream>>>(
        p0, p1, p2, a0, a1, a2, gtb, gtl, ws_f, ws_i);
    final_kernel<<<1, 64, 0, stream>>>(ws_f, ws_i, out);
}